// Round 7
// baseline (129.204 us; speedup 1.0000x reference)
//
#include <hip/hip_runtime.h>

// Tucker scoring: out[n] = sum_{p,q,r} U[i_n,p] V[j_n,q] W[k_n,r] G[p,q,r]
// P=Q=R=32, N=131072, num_time=5000.
//
// Round 11: revert round-10's cooperative prepare (harness failure: coop
// launch inside graph capture / grid.sync at 1137 blocks). Back to the
// proven round-9 pipeline (126.1us):
//   memset(20KB) -> fused_prepare (build_H + scatter) -> tucker_eval_bpk.
// Keep round-10's one safe improvement, previously untested:
//   eval stages ALL BIN_CAP records unconditionally (slots >= m hold poison,
//   consumption guarded by s<m), so counts/H/record loads issue concurrently
//   at block start -- no serial counts->records dependency.

#define BIN_CAP 128

// ---------------------------------------------------------------------------
// build_H block body: H[k][pq] = sum_r G[pq][r] * W[k][r], 8 k per block
// ---------------------------------------------------------------------------
__device__ __forceinline__ void build_H_body(const float* __restrict__ G,
                                             const float* __restrict__ W,
                                             float* __restrict__ H,
                                             int num_time, int bblk) {
    const int pq4 = threadIdx.x;            // owns pq in [4*pq4, 4*pq4+4)
    const int kbase = bblk * 8;

    float acc[8][4];
#pragma unroll
    for (int kk = 0; kk < 8; ++kk)
#pragma unroll
        for (int i = 0; i < 4; ++i) acc[kk][i] = 0.f;

#pragma unroll
    for (int r4 = 0; r4 < 8; ++r4) {
        float4 g[4];
#pragma unroll
        for (int i = 0; i < 4; ++i)
            g[i] = *(const float4*)(G + (size_t)(pq4 * 4 + i) * 32 + r4 * 4);
#pragma unroll
        for (int kk = 0; kk < 8; ++kk) {
            int k = kbase + kk;
            int kc = (k < num_time) ? k : (num_time - 1);
            float4 w = *(const float4*)(W + (size_t)kc * 32 + r4 * 4);
#pragma unroll
            for (int i = 0; i < 4; ++i)
                acc[kk][i] += g[i].x * w.x + g[i].y * w.y + g[i].z * w.z + g[i].w * w.w;
        }
    }

#pragma unroll
    for (int kk = 0; kk < 8; ++kk) {
        int k = kbase + kk;
        if (k < num_time) {
            float4 o = make_float4(acc[kk][0], acc[kk][1], acc[kk][2], acc[kk][3]);
            *(float4*)(H + (size_t)k * 1024 + pq4 * 4) = o;
        }
    }
}

// ---------------------------------------------------------------------------
// scatter block body: bin samples by k with packed records {n, i, j, k}
// ---------------------------------------------------------------------------
__device__ __forceinline__ void scatter_body(const int* __restrict__ K,
                                             const int* __restrict__ I,
                                             const int* __restrict__ J,
                                             int* __restrict__ counts,
                                             int4* __restrict__ bins,
                                             int* __restrict__ ovf_cnt,
                                             int4* __restrict__ ovf,
                                             int n, int sblk, int nsblk) {
    for (int idx = sblk * 256 + (int)threadIdx.x; idx < n; idx += nsblk * 256) {
        int k = K[idx];
        int4 rec = make_int4(idx, I[idx], J[idx], k);
        int pos = atomicAdd(&counts[k], 1);
        if (pos < BIN_CAP) {
            bins[(size_t)k * BIN_CAP + pos] = rec;
        } else {
            int o = atomicAdd(ovf_cnt, 1);
            ovf[o] = rec;
        }
    }
}

// ---------------------------------------------------------------------------
// fused_prepare: blocks [0,nbuild) run build_H, blocks [nbuild,...) scatter.
// ---------------------------------------------------------------------------
__global__ __launch_bounds__(256) void fused_prepare(
        const float* __restrict__ G, const float* __restrict__ W,
        float* __restrict__ H,
        const int* __restrict__ K, const int* __restrict__ I,
        const int* __restrict__ J, int* __restrict__ counts,
        int4* __restrict__ bins, int* __restrict__ ovf_cnt,
        int4* __restrict__ ovf, int n, int num_time,
        int nbuild, int nscatter) {
    const int b = (int)blockIdx.x;
    if (b < nbuild) {
        build_H_body(G, W, H, num_time, b);
    } else {
        scatter_body(K, I, J, counts, bins, ovf_cnt, ovf, n, b - nbuild, nscatter);
    }
}

// Standalone build_H (mid-tier fallback path)
__global__ __launch_bounds__(256) void build_H(const float* __restrict__ G,
                                               const float* __restrict__ W,
                                               float* __restrict__ H,
                                               int num_time) {
    build_H_body(G, W, H, num_time, blockIdx.x);
}

// ---------------------------------------------------------------------------
// eval: block per k (grid = num_time). H[k] 4KB -> LDS (coalesced), bin
// records -> LDS unconditionally (poison in slots >= m never consumed).
// 32 samples in flight: 8-lane group per sample; per lane
// acc4 = sum_p u_p * H[p][4qq..4qq+3] via conflict-free LDS broadcasts;
// dot with v4; reduce via shfl_xor 1/2/4. Typical m~26 -> one iteration.
// Overflow drained grid-stride (global H).
// ---------------------------------------------------------------------------
__global__ __launch_bounds__(256) void tucker_eval_bpk(
        const float* __restrict__ U, const float* __restrict__ V,
        const float* __restrict__ H, const int* __restrict__ counts,
        const int4* __restrict__ bins, float* __restrict__ out,
        int num_time, const int* __restrict__ ovf_cnt,
        const int4* __restrict__ ovf) {
    __shared__ float4 Hs[256];               // 4 KB: H row for this k
    __shared__ int4 Rs[BIN_CAP];             // 2 KB: staged records
    const int tid = threadIdx.x;
    const int k = (int)blockIdx.x;
    const int qq = tid & 7;                  // q-quad within sample group
    const int g = tid >> 3;                  // sample group 0..31

    // All block-start loads issue concurrently (no serial chain):
    int m = counts[k];                       // scalar
    const float4* __restrict__ Hrow = (const float4*)(H + (size_t)k * 1024);
    Hs[tid] = Hrow[tid];                     // 4KB coalesced
    if (tid < BIN_CAP)                       // unconditional (not m-gated)
        Rs[tid] = bins[(size_t)k * BIN_CAP + tid];
    m = (m < BIN_CAP) ? m : BIN_CAP;
    __syncthreads();

    for (int s0 = 0; s0 < m; s0 += 32) {
        const int s = s0 + g;                // group-uniform
        if (s < m) {
            int4 rec = Rs[s];
            const float4* __restrict__ Ur = (const float4*)(U + (size_t)rec.y * 32);
            float4 u[8];
#pragma unroll
            for (int p4 = 0; p4 < 8; ++p4) u[p4] = Ur[p4];
            float4 v4 = ((const float4*)(V + (size_t)rec.z * 32))[qq];

            float4 acc = make_float4(0.f, 0.f, 0.f, 0.f);
#pragma unroll
            for (int p4 = 0; p4 < 8; ++p4) {
                float4 h;
                h = Hs[(p4 * 4 + 0) * 8 + qq];
                acc.x += u[p4].x * h.x; acc.y += u[p4].x * h.y;
                acc.z += u[p4].x * h.z; acc.w += u[p4].x * h.w;
                h = Hs[(p4 * 4 + 1) * 8 + qq];
                acc.x += u[p4].y * h.x; acc.y += u[p4].y * h.y;
                acc.z += u[p4].y * h.z; acc.w += u[p4].y * h.w;
                h = Hs[(p4 * 4 + 2) * 8 + qq];
                acc.x += u[p4].z * h.x; acc.y += u[p4].z * h.y;
                acc.z += u[p4].z * h.z; acc.w += u[p4].z * h.w;
                h = Hs[(p4 * 4 + 3) * 8 + qq];
                acc.x += u[p4].w * h.x; acc.y += u[p4].w * h.y;
                acc.z += u[p4].w * h.z; acc.w += u[p4].w * h.w;
            }
            float sd = acc.x * v4.x + acc.y * v4.y + acc.z * v4.z + acc.w * v4.w;
            sd += __shfl_xor(sd, 1, 64);
            sd += __shfl_xor(sd, 2, 64);
            sd += __shfl_xor(sd, 4, 64);
            if (qq == 0) out[rec.x] = sd;
        }
    }

    // --------- overflow drain (rare/never): wave per spill record ---------
    const int cnt = *ovf_cnt;
    if (cnt > 0) {
        const int wave = tid >> 6;
        const int lane = tid & 63;
        const int gwave = k * 4 + wave;
        const int nw = (int)gridDim.x * 4;
        const int pg = lane >> 3;
        const int qq6 = lane & 7;
        for (int s = gwave; s < cnt; s += nw) {
            int4 rec = ovf[s];
            const float4* __restrict__ Hrow2 = (const float4*)(H + (size_t)rec.w * 1024);
            const float* __restrict__ Ur = U + (size_t)rec.y * 32;

            float4 acc = make_float4(0.f, 0.f, 0.f, 0.f);
#pragma unroll
            for (int it = 0; it < 4; ++it) {
                float4 h = Hrow2[lane + it * 64];
                float up = Ur[pg + it * 8];
                acc.x += up * h.x; acc.y += up * h.y;
                acc.z += up * h.z; acc.w += up * h.w;
            }
#pragma unroll
            for (int off = 8; off < 64; off <<= 1) {
                acc.x += __shfl_xor(acc.x, off, 64);
                acc.y += __shfl_xor(acc.y, off, 64);
                acc.z += __shfl_xor(acc.z, off, 64);
                acc.w += __shfl_xor(acc.w, off, 64);
            }
            float4 v4 = ((const float4*)(V + (size_t)rec.z * 32))[qq6];
            float sd = acc.x * v4.x + acc.y * v4.y + acc.z * v4.z + acc.w * v4.w;
            sd += __shfl_xor(sd, 1, 64);
            sd += __shfl_xor(sd, 2, 64);
            sd += __shfl_xor(sd, 4, 64);
            if (lane == 0) out[rec.x] = sd;
        }
    }
}

// ---------------------------------------------------------------------------
// Fallbacks for small workspace
// ---------------------------------------------------------------------------
__global__ __launch_bounds__(256) void tucker_eval(const int* __restrict__ I,
                                                   const int* __restrict__ J,
                                                   const int* __restrict__ K,
                                                   const float* __restrict__ U,
                                                   const float* __restrict__ V,
                                                   const float* __restrict__ H,
                                                   float* __restrict__ out,
                                                   int n_samples) {
    const int wave = (int)((blockIdx.x * (unsigned)blockDim.x + threadIdx.x) >> 6);
    const int lane = threadIdx.x & 63;
    if (wave >= n_samples) return;
    const int i = I[wave];
    const int j = J[wave];
    const int k = K[wave];
    const int qq = lane & 7;
    const int pg = lane >> 3;
    const float4* __restrict__ Hrow = (const float4*)(H + (size_t)k * 1024);
    const float* __restrict__ Urow = U + (size_t)i * 32;
    float4 acc = make_float4(0.f, 0.f, 0.f, 0.f);
#pragma unroll
    for (int it = 0; it < 4; ++it) {
        float4 h = Hrow[lane + it * 64];
        float up = Urow[pg + it * 8];
        acc.x += up * h.x; acc.y += up * h.y;
        acc.z += up * h.z; acc.w += up * h.w;
    }
#pragma unroll
    for (int off = 8; off < 64; off <<= 1) {
        acc.x += __shfl_xor(acc.x, off, 64);
        acc.y += __shfl_xor(acc.y, off, 64);
        acc.z += __shfl_xor(acc.z, off, 64);
        acc.w += __shfl_xor(acc.w, off, 64);
    }
    float4 v4 = ((const float4*)(V + (size_t)j * 32))[qq];
    float s = acc.x * v4.x + acc.y * v4.y + acc.z * v4.z + acc.w * v4.w;
    s += __shfl_xor(s, 1, 64);
    s += __shfl_xor(s, 2, 64);
    s += __shfl_xor(s, 4, 64);
    if (lane == 0) out[wave] = s;
}

__global__ __launch_bounds__(256) void tucker_direct(const int* __restrict__ I,
                                                     const int* __restrict__ J,
                                                     const int* __restrict__ K,
                                                     const float* __restrict__ U,
                                                     const float* __restrict__ V,
                                                     const float* __restrict__ W,
                                                     const float* __restrict__ G,
                                                     float* __restrict__ out,
                                                     int n_samples) {
    __shared__ float Gc[4 * 32 * 32];
    const int n = blockIdx.x * blockDim.x + threadIdx.x;
    const bool active = (n < n_samples);
    int i = 0, j = 0, k = 0;
    if (active) { i = I[n]; j = J[n]; k = K[n]; }
    float4 w4[8];
#pragma unroll
    for (int r4 = 0; r4 < 8; ++r4)
        w4[r4] = ((const float4*)(W + (size_t)k * 32))[r4];
    float v[32];
#pragma unroll
    for (int q4 = 0; q4 < 8; ++q4) {
        float4 t = ((const float4*)(V + (size_t)j * 32))[q4];
        v[q4 * 4 + 0] = t.x; v[q4 * 4 + 1] = t.y;
        v[q4 * 4 + 2] = t.z; v[q4 * 4 + 3] = t.w;
    }
    const float* __restrict__ Urow = U + (size_t)i * 32;
    float acc = 0.f;
    for (int c = 0; c < 8; ++c) {
        __syncthreads();
#pragma unroll
        for (int t = 0; t < 4; ++t) {
            int idx = threadIdx.x + t * 256;
            ((float4*)Gc)[idx] = ((const float4*)(G + (size_t)c * 4096))[idx];
        }
        __syncthreads();
        for (int pp = 0; pp < 4; ++pp) {
            float up = Urow[c * 4 + pp];
#pragma unroll
            for (int q = 0; q < 32; ++q) {
                float t0 = 0.f;
#pragma unroll
                for (int r4 = 0; r4 < 8; ++r4) {
                    float4 g = ((const float4*)Gc)[pp * 256 + q * 8 + r4];
                    t0 += g.x * w4[r4].x + g.y * w4[r4].y + g.z * w4[r4].z + g.w * w4[r4].w;
                }
                acc += up * v[q] * t0;
            }
        }
    }
    if (active) out[n] = acc;
}

extern "C" void kernel_launch(void* const* d_in, const int* in_sizes, int n_in,
                              void* d_out, int out_size, void* d_ws, size_t ws_size,
                              hipStream_t stream) {
    const int*   I = (const int*)d_in[0];
    const int*   J = (const int*)d_in[1];
    const int*   K = (const int*)d_in[2];
    const float* U = (const float*)d_in[3];   // [NUM_USER, 32]
    const float* V = (const float*)d_in[4];   // [NUM_ITEM, 32]
    const float* W = (const float*)d_in[5];   // [NUM_TIME, 32]
    const float* G = (const float*)d_in[6];   // [32, 32, 32]
    float* out = (float*)d_out;

    const int n_samples = in_sizes[0];
    const int num_time = in_sizes[5] / 32;

    const size_t h_bytes = (size_t)num_time * 1024 * sizeof(float);
    const size_t z_bytes = (size_t)(num_time + 1) * sizeof(int);   // counts + ovf_cnt
    const size_t z_pad = (z_bytes + 15) & ~(size_t)15;
    const size_t bins_bytes = (size_t)num_time * BIN_CAP * sizeof(int4);
    const size_t ovf_bytes = (size_t)n_samples * sizeof(int4);
    const size_t need_full = h_bytes + z_pad + bins_bytes + ovf_bytes;

    if (ws_size >= need_full) {
        float* H       = (float*)d_ws;
        int*   counts  = (int*)((char*)d_ws + h_bytes);      // num_time
        int*   ovf_cnt = counts + num_time;                  // 1 (contiguous)
        int4*  bins    = (int4*)((char*)d_ws + h_bytes + z_pad);
        int4*  ovf     = (int4*)((char*)d_ws + h_bytes + z_pad + bins_bytes);

        const int nbuild = (num_time + 7) / 8;
        const int nscatter = 512;

        hipMemsetAsync(counts, 0, z_bytes, stream);
        fused_prepare<<<nbuild + nscatter, 256, 0, stream>>>(
            G, W, H, K, I, J, counts, bins, ovf_cnt, ovf,
            n_samples, num_time, nbuild, nscatter);
        tucker_eval_bpk<<<num_time, 256, 0, stream>>>(
            U, V, H, counts, bins, out, num_time, ovf_cnt, ovf);
    } else if (ws_size >= h_bytes) {
        float* H = (float*)d_ws;
        build_H<<<(num_time + 7) / 8, 256, 0, stream>>>(G, W, H, num_time);
        const long long total_threads = (long long)n_samples * 64;
        tucker_eval<<<(int)((total_threads + 255) / 256), 256, 0, stream>>>(
            I, J, K, U, V, H, out, n_samples);
    } else {
        tucker_direct<<<(n_samples + 255) / 256, 256, 0, stream>>>(
            I, J, K, U, V, W, G, out, n_samples);
    }
}

// Round 8
// 123.910 us; speedup vs baseline: 1.0427x; 1.0427x over previous
//
#include <hip/hip_runtime.h>

// Tucker scoring: out[n] = sum_{p,q,r} U[i_n,p] V[j_n,q] W[k_n,r] G[p,q,r]
// P=Q=R=32, N=131072, num_time=5000.
//
// Round 12: revert round-11's unconditional record staging (+8MB bins
// traffic, +3.1us real). Back to round-9's m-gated staging (126.1us), plus
// one epoch cut on eval's critical path: iteration-0 records are loaded
// DIRECTLY from global (bins[k*CAP+g], known address) before the barrier,
// and the U/V gathers issue as soon as that record lands -- overlapping the
// H-stage + __syncthreads instead of serializing behind them. (R5 showed
// each removed serial epoch ~ -4us.) Iterations >=1 (m>32, ~10% of blocks)
// use the staged-LDS path unchanged. Poison-safe: record fields clamped by
// (g<m) before addressing; consumption/stores guarded by s<m.
// Pipeline: memset(20KB) -> fused_prepare (build_H + scatter) -> eval_bpk.

#define BIN_CAP 128

// ---------------------------------------------------------------------------
// build_H block body: H[k][pq] = sum_r G[pq][r] * W[k][r], 8 k per block
// ---------------------------------------------------------------------------
__device__ __forceinline__ void build_H_body(const float* __restrict__ G,
                                             const float* __restrict__ W,
                                             float* __restrict__ H,
                                             int num_time, int bblk) {
    const int pq4 = threadIdx.x;            // owns pq in [4*pq4, 4*pq4+4)
    const int kbase = bblk * 8;

    float acc[8][4];
#pragma unroll
    for (int kk = 0; kk < 8; ++kk)
#pragma unroll
        for (int i = 0; i < 4; ++i) acc[kk][i] = 0.f;

#pragma unroll
    for (int r4 = 0; r4 < 8; ++r4) {
        float4 g[4];
#pragma unroll
        for (int i = 0; i < 4; ++i)
            g[i] = *(const float4*)(G + (size_t)(pq4 * 4 + i) * 32 + r4 * 4);
#pragma unroll
        for (int kk = 0; kk < 8; ++kk) {
            int k = kbase + kk;
            int kc = (k < num_time) ? k : (num_time - 1);
            float4 w = *(const float4*)(W + (size_t)kc * 32 + r4 * 4);
#pragma unroll
            for (int i = 0; i < 4; ++i)
                acc[kk][i] += g[i].x * w.x + g[i].y * w.y + g[i].z * w.z + g[i].w * w.w;
        }
    }

#pragma unroll
    for (int kk = 0; kk < 8; ++kk) {
        int k = kbase + kk;
        if (k < num_time) {
            float4 o = make_float4(acc[kk][0], acc[kk][1], acc[kk][2], acc[kk][3]);
            *(float4*)(H + (size_t)k * 1024 + pq4 * 4) = o;
        }
    }
}

// ---------------------------------------------------------------------------
// scatter block body: bin samples by k with packed records {n, i, j, k}
// ---------------------------------------------------------------------------
__device__ __forceinline__ void scatter_body(const int* __restrict__ K,
                                             const int* __restrict__ I,
                                             const int* __restrict__ J,
                                             int* __restrict__ counts,
                                             int4* __restrict__ bins,
                                             int* __restrict__ ovf_cnt,
                                             int4* __restrict__ ovf,
                                             int n, int sblk, int nsblk) {
    for (int idx = sblk * 256 + (int)threadIdx.x; idx < n; idx += nsblk * 256) {
        int k = K[idx];
        int4 rec = make_int4(idx, I[idx], J[idx], k);
        int pos = atomicAdd(&counts[k], 1);
        if (pos < BIN_CAP) {
            bins[(size_t)k * BIN_CAP + pos] = rec;
        } else {
            int o = atomicAdd(ovf_cnt, 1);
            ovf[o] = rec;
        }
    }
}

// ---------------------------------------------------------------------------
// fused_prepare: blocks [0,nbuild) run build_H, blocks [nbuild,...) scatter.
// ---------------------------------------------------------------------------
__global__ __launch_bounds__(256) void fused_prepare(
        const float* __restrict__ G, const float* __restrict__ W,
        float* __restrict__ H,
        const int* __restrict__ K, const int* __restrict__ I,
        const int* __restrict__ J, int* __restrict__ counts,
        int4* __restrict__ bins, int* __restrict__ ovf_cnt,
        int4* __restrict__ ovf, int n, int num_time,
        int nbuild, int nscatter) {
    const int b = (int)blockIdx.x;
    if (b < nbuild) {
        build_H_body(G, W, H, num_time, b);
    } else {
        scatter_body(K, I, J, counts, bins, ovf_cnt, ovf, n, b - nbuild, nscatter);
    }
}

// Standalone build_H (mid-tier fallback path)
__global__ __launch_bounds__(256) void build_H(const float* __restrict__ G,
                                               const float* __restrict__ W,
                                               float* __restrict__ H,
                                               int num_time) {
    build_H_body(G, W, H, num_time, blockIdx.x);
}

// ---------------------------------------------------------------------------
// eval: block per k (grid = num_time). H[k] 4KB -> LDS (coalesced).
// Iteration 0 (covers m<=32, ~90% of blocks entirely): record for group g
// loaded directly from bins[k*CAP+g] pre-barrier; U/V gathers issue behind
// it, overlapping H-stage + barrier. Iterations >=1 use m-gated LDS-staged
// records. 32 samples in flight (8-lane group per sample); per lane
// acc4 = sum_p u_p * H[p][4qq..4qq+3] via conflict-free LDS broadcasts;
// dot with v4; reduce via shfl_xor 1/2/4. Overflow drained grid-stride.
// ---------------------------------------------------------------------------
__global__ __launch_bounds__(256) void tucker_eval_bpk(
        const float* __restrict__ U, const float* __restrict__ V,
        const float* __restrict__ H, const int* __restrict__ counts,
        const int4* __restrict__ bins, float* __restrict__ out,
        int num_time, const int* __restrict__ ovf_cnt,
        const int4* __restrict__ ovf) {
    __shared__ float4 Hs[256];               // 4 KB: H row for this k
    __shared__ int4 Rs[BIN_CAP];             // 2 KB: staged records (iter>=1)
    const int tid = threadIdx.x;
    const int k = (int)blockIdx.x;
    const int qq = tid & 7;                  // q-quad within sample group
    const int g = tid >> 3;                  // sample group 0..31

    // Issue all independent block-start loads:
    int m = counts[k];                       // scalar
    const float4* __restrict__ Hrow = (const float4*)(H + (size_t)k * 1024);
    float4 hreg = Hrow[tid];                 // H-stage load (4KB coalesced)
    int4 rec0 = bins[(size_t)k * BIN_CAP + g]; // iter-0 record, direct (g<32)
    m = (m < BIN_CAP) ? m : BIN_CAP;
    if (tid < m) Rs[tid] = bins[(size_t)k * BIN_CAP + tid]; // iter>=1 path

    // Iter-0 U/V gathers issue as soon as rec0+m land (no barrier in chain).
    // Clamp addresses against poison for inactive groups (g >= m).
    const bool act0 = (g < m);
    const int ri0 = act0 ? rec0.y : 0;
    const int rj0 = act0 ? rec0.z : 0;
    float4 u[8];
    {
        const float4* __restrict__ Ur = (const float4*)(U + (size_t)ri0 * 32);
#pragma unroll
        for (int p4 = 0; p4 < 8; ++p4) u[p4] = Ur[p4];
    }
    float4 v4 = ((const float4*)(V + (size_t)rj0 * 32))[qq];

    Hs[tid] = hreg;                          // LDS write once hreg arrives
    __syncthreads();

    // ---------------- iteration 0 (s = g) ----------------
    if (act0) {
        float4 acc = make_float4(0.f, 0.f, 0.f, 0.f);
#pragma unroll
        for (int p4 = 0; p4 < 8; ++p4) {
            float4 h;
            h = Hs[(p4 * 4 + 0) * 8 + qq];
            acc.x += u[p4].x * h.x; acc.y += u[p4].x * h.y;
            acc.z += u[p4].x * h.z; acc.w += u[p4].x * h.w;
            h = Hs[(p4 * 4 + 1) * 8 + qq];
            acc.x += u[p4].y * h.x; acc.y += u[p4].y * h.y;
            acc.z += u[p4].y * h.z; acc.w += u[p4].y * h.w;
            h = Hs[(p4 * 4 + 2) * 8 + qq];
            acc.x += u[p4].z * h.x; acc.y += u[p4].z * h.y;
            acc.z += u[p4].z * h.z; acc.w += u[p4].z * h.w;
            h = Hs[(p4 * 4 + 3) * 8 + qq];
            acc.x += u[p4].w * h.x; acc.y += u[p4].w * h.y;
            acc.z += u[p4].w * h.z; acc.w += u[p4].w * h.w;
        }
        float sd = acc.x * v4.x + acc.y * v4.y + acc.z * v4.z + acc.w * v4.w;
        sd += __shfl_xor(sd, 1, 64);
        sd += __shfl_xor(sd, 2, 64);
        sd += __shfl_xor(sd, 4, 64);
        if (qq == 0) out[rec0.x] = sd;
    }

    // ---------------- iterations >= 1 (m > 32, ~10% of blocks) ----------------
    for (int s0 = 32; s0 < m; s0 += 32) {
        const int s = s0 + g;
        if (s < m) {
            int4 rec = Rs[s];
            const float4* __restrict__ Ur = (const float4*)(U + (size_t)rec.y * 32);
            float4 u1[8];
#pragma unroll
            for (int p4 = 0; p4 < 8; ++p4) u1[p4] = Ur[p4];
            float4 v1 = ((const float4*)(V + (size_t)rec.z * 32))[qq];

            float4 acc = make_float4(0.f, 0.f, 0.f, 0.f);
#pragma unroll
            for (int p4 = 0; p4 < 8; ++p4) {
                float4 h;
                h = Hs[(p4 * 4 + 0) * 8 + qq];
                acc.x += u1[p4].x * h.x; acc.y += u1[p4].x * h.y;
                acc.z += u1[p4].x * h.z; acc.w += u1[p4].x * h.w;
                h = Hs[(p4 * 4 + 1) * 8 + qq];
                acc.x += u1[p4].y * h.x; acc.y += u1[p4].y * h.y;
                acc.z += u1[p4].y * h.z; acc.w += u1[p4].y * h.w;
                h = Hs[(p4 * 4 + 2) * 8 + qq];
                acc.x += u1[p4].z * h.x; acc.y += u1[p4].z * h.y;
                acc.z += u1[p4].z * h.z; acc.w += u1[p4].z * h.w;
                h = Hs[(p4 * 4 + 3) * 8 + qq];
                acc.x += u1[p4].w * h.x; acc.y += u1[p4].w * h.y;
                acc.z += u1[p4].w * h.z; acc.w += u1[p4].w * h.w;
            }
            float sd = acc.x * v1.x + acc.y * v1.y + acc.z * v1.z + acc.w * v1.w;
            sd += __shfl_xor(sd, 1, 64);
            sd += __shfl_xor(sd, 2, 64);
            sd += __shfl_xor(sd, 4, 64);
            if (qq == 0) out[rec.x] = sd;
        }
    }

    // --------- overflow drain (rare/never): wave per spill record ---------
    const int cnt = *ovf_cnt;
    if (cnt > 0) {
        const int wave = tid >> 6;
        const int lane = tid & 63;
        const int gwave = k * 4 + wave;
        const int nw = (int)gridDim.x * 4;
        const int pg = lane >> 3;
        const int qq6 = lane & 7;
        for (int s = gwave; s < cnt; s += nw) {
            int4 rec = ovf[s];
            const float4* __restrict__ Hrow2 = (const float4*)(H + (size_t)rec.w * 1024);
            const float* __restrict__ Ur = U + (size_t)rec.y * 32;

            float4 acc = make_float4(0.f, 0.f, 0.f, 0.f);
#pragma unroll
            for (int it = 0; it < 4; ++it) {
                float4 h = Hrow2[lane + it * 64];
                float up = Ur[pg + it * 8];
                acc.x += up * h.x; acc.y += up * h.y;
                acc.z += up * h.z; acc.w += up * h.w;
            }
#pragma unroll
            for (int off = 8; off < 64; off <<= 1) {
                acc.x += __shfl_xor(acc.x, off, 64);
                acc.y += __shfl_xor(acc.y, off, 64);
                acc.z += __shfl_xor(acc.z, off, 64);
                acc.w += __shfl_xor(acc.w, off, 64);
            }
            float4 v4o = ((const float4*)(V + (size_t)rec.z * 32))[qq6];
            float sd = acc.x * v4o.x + acc.y * v4o.y + acc.z * v4o.z + acc.w * v4o.w;
            sd += __shfl_xor(sd, 1, 64);
            sd += __shfl_xor(sd, 2, 64);
            sd += __shfl_xor(sd, 4, 64);
            if (lane == 0) out[rec.x] = sd;
        }
    }
}

// ---------------------------------------------------------------------------
// Fallbacks for small workspace
// ---------------------------------------------------------------------------
__global__ __launch_bounds__(256) void tucker_eval(const int* __restrict__ I,
                                                   const int* __restrict__ J,
                                                   const int* __restrict__ K,
                                                   const float* __restrict__ U,
                                                   const float* __restrict__ V,
                                                   const float* __restrict__ H,
                                                   float* __restrict__ out,
                                                   int n_samples) {
    const int wave = (int)((blockIdx.x * (unsigned)blockDim.x + threadIdx.x) >> 6);
    const int lane = threadIdx.x & 63;
    if (wave >= n_samples) return;
    const int i = I[wave];
    const int j = J[wave];
    const int k = K[wave];
    const int qq = lane & 7;
    const int pg = lane >> 3;
    const float4* __restrict__ Hrow = (const float4*)(H + (size_t)k * 1024);
    const float* __restrict__ Urow = U + (size_t)i * 32;
    float4 acc = make_float4(0.f, 0.f, 0.f, 0.f);
#pragma unroll
    for (int it = 0; it < 4; ++it) {
        float4 h = Hrow[lane + it * 64];
        float up = Urow[pg + it * 8];
        acc.x += up * h.x; acc.y += up * h.y;
        acc.z += up * h.z; acc.w += up * h.w;
    }
#pragma unroll
    for (int off = 8; off < 64; off <<= 1) {
        acc.x += __shfl_xor(acc.x, off, 64);
        acc.y += __shfl_xor(acc.y, off, 64);
        acc.z += __shfl_xor(acc.z, off, 64);
        acc.w += __shfl_xor(acc.w, off, 64);
    }
    float4 v4 = ((const float4*)(V + (size_t)j * 32))[qq];
    float s = acc.x * v4.x + acc.y * v4.y + acc.z * v4.z + acc.w * v4.w;
    s += __shfl_xor(s, 1, 64);
    s += __shfl_xor(s, 2, 64);
    s += __shfl_xor(s, 4, 64);
    if (lane == 0) out[wave] = s;
}

__global__ __launch_bounds__(256) void tucker_direct(const int* __restrict__ I,
                                                     const int* __restrict__ J,
                                                     const int* __restrict__ K,
                                                     const float* __restrict__ U,
                                                     const float* __restrict__ V,
                                                     const float* __restrict__ W,
                                                     const float* __restrict__ G,
                                                     float* __restrict__ out,
                                                     int n_samples) {
    __shared__ float Gc[4 * 32 * 32];
    const int n = blockIdx.x * blockDim.x + threadIdx.x;
    const bool active = (n < n_samples);
    int i = 0, j = 0, k = 0;
    if (active) { i = I[n]; j = J[n]; k = K[n]; }
    float4 w4[8];
#pragma unroll
    for (int r4 = 0; r4 < 8; ++r4)
        w4[r4] = ((const float4*)(W + (size_t)k * 32))[r4];
    float v[32];
#pragma unroll
    for (int q4 = 0; q4 < 8; ++q4) {
        float4 t = ((const float4*)(V + (size_t)j * 32))[q4];
        v[q4 * 4 + 0] = t.x; v[q4 * 4 + 1] = t.y;
        v[q4 * 4 + 2] = t.z; v[q4 * 4 + 3] = t.w;
    }
    const float* __restrict__ Urow = U + (size_t)i * 32;
    float acc = 0.f;
    for (int c = 0; c < 8; ++c) {
        __syncthreads();
#pragma unroll
        for (int t = 0; t < 4; ++t) {
            int idx = threadIdx.x + t * 256;
            ((float4*)Gc)[idx] = ((const float4*)(G + (size_t)c * 4096))[idx];
        }
        __syncthreads();
        for (int pp = 0; pp < 4; ++pp) {
            float up = Urow[c * 4 + pp];
#pragma unroll
            for (int q = 0; q < 32; ++q) {
                float t0 = 0.f;
#pragma unroll
                for (int r4 = 0; r4 < 8; ++r4) {
                    float4 g = ((const float4*)Gc)[pp * 256 + q * 8 + r4];
                    t0 += g.x * w4[r4].x + g.y * w4[r4].y + g.z * w4[r4].z + g.w * w4[r4].w;
                }
                acc += up * v[q] * t0;
            }
        }
    }
    if (active) out[n] = acc;
}

extern "C" void kernel_launch(void* const* d_in, const int* in_sizes, int n_in,
                              void* d_out, int out_size, void* d_ws, size_t ws_size,
                              hipStream_t stream) {
    const int*   I = (const int*)d_in[0];
    const int*   J = (const int*)d_in[1];
    const int*   K = (const int*)d_in[2];
    const float* U = (const float*)d_in[3];   // [NUM_USER, 32]
    const float* V = (const float*)d_in[4];   // [NUM_ITEM, 32]
    const float* W = (const float*)d_in[5];   // [NUM_TIME, 32]
    const float* G = (const float*)d_in[6];   // [32, 32, 32]
    float* out = (float*)d_out;

    const int n_samples = in_sizes[0];
    const int num_time = in_sizes[5] / 32;

    const size_t h_bytes = (size_t)num_time * 1024 * sizeof(float);
    const size_t z_bytes = (size_t)(num_time + 1) * sizeof(int);   // counts + ovf_cnt
    const size_t z_pad = (z_bytes + 15) & ~(size_t)15;
    const size_t bins_bytes = (size_t)num_time * BIN_CAP * sizeof(int4);
    const size_t ovf_bytes = (size_t)n_samples * sizeof(int4);
    const size_t need_full = h_bytes + z_pad + bins_bytes + ovf_bytes;

    if (ws_size >= need_full) {
        float* H       = (float*)d_ws;
        int*   counts  = (int*)((char*)d_ws + h_bytes);      // num_time
        int*   ovf_cnt = counts + num_time;                  // 1 (contiguous)
        int4*  bins    = (int4*)((char*)d_ws + h_bytes + z_pad);
        int4*  ovf     = (int4*)((char*)d_ws + h_bytes + z_pad + bins_bytes);

        const int nbuild = (num_time + 7) / 8;
        const int nscatter = 512;

        hipMemsetAsync(counts, 0, z_bytes, stream);
        fused_prepare<<<nbuild + nscatter, 256, 0, stream>>>(
            G, W, H, K, I, J, counts, bins, ovf_cnt, ovf,
            n_samples, num_time, nbuild, nscatter);
        tucker_eval_bpk<<<num_time, 256, 0, stream>>>(
            U, V, H, counts, bins, out, num_time, ovf_cnt, ovf);
    } else if (ws_size >= h_bytes) {
        float* H = (float*)d_ws;
        build_H<<<(num_time + 7) / 8, 256, 0, stream>>>(G, W, H, num_time);
        const long long total_threads = (long long)n_samples * 64;
        tucker_eval<<<(int)((total_threads + 255) / 256), 256, 0, stream>>>(
            I, J, K, U, V, H, out, n_samples);
    } else {
        tucker_direct<<<(n_samples + 255) / 256, 256, 0, stream>>>(
            I, J, K, U, V, W, G, out, n_samples);
    }
}

// Round 9
// 122.744 us; speedup vs baseline: 1.0526x; 1.0095x over previous
//
#include <hip/hip_runtime.h>

// Tucker scoring: out[n] = sum_{p,q,r} U[i_n,p] V[j_n,q] W[k_n,r] G[p,q,r]
// P=Q=R=32, N=131072, num_time=5000.
//
// Round 13: eval record-path cleanup on the round-12 winner (123.9us).
//   - Rs LDS buffer deleted: iterations >=1 read bins[k*CAP+s] directly
//     (8-lane-group broadcast of one 16B line) instead of staging all m
//     records through LDS -- removes ~2.6MB of duplicated slot-0..31 loads
//     and the Rs write+read dependency.
//   - Iteration-1 record prefetched pre-barrier (predicated, +4 VGPR) so its
//     U/V gathers can overlap iteration-0 compute (affects the ~11% of
//     blocks with m>32).
//   - Iteration 0 unchanged from round 12: rec0 direct load + pre-barrier
//     U/V gathers overlapping the H-stage + __syncthreads.
// Pipeline: memset(20KB) -> fused_prepare (build_H + scatter) -> eval_bpk.

#define BIN_CAP 128

// ---------------------------------------------------------------------------
// build_H block body: H[k][pq] = sum_r G[pq][r] * W[k][r], 8 k per block
// ---------------------------------------------------------------------------
__device__ __forceinline__ void build_H_body(const float* __restrict__ G,
                                             const float* __restrict__ W,
                                             float* __restrict__ H,
                                             int num_time, int bblk) {
    const int pq4 = threadIdx.x;            // owns pq in [4*pq4, 4*pq4+4)
    const int kbase = bblk * 8;

    float acc[8][4];
#pragma unroll
    for (int kk = 0; kk < 8; ++kk)
#pragma unroll
        for (int i = 0; i < 4; ++i) acc[kk][i] = 0.f;

#pragma unroll
    for (int r4 = 0; r4 < 8; ++r4) {
        float4 g[4];
#pragma unroll
        for (int i = 0; i < 4; ++i)
            g[i] = *(const float4*)(G + (size_t)(pq4 * 4 + i) * 32 + r4 * 4);
#pragma unroll
        for (int kk = 0; kk < 8; ++kk) {
            int k = kbase + kk;
            int kc = (k < num_time) ? k : (num_time - 1);
            float4 w = *(const float4*)(W + (size_t)kc * 32 + r4 * 4);
#pragma unroll
            for (int i = 0; i < 4; ++i)
                acc[kk][i] += g[i].x * w.x + g[i].y * w.y + g[i].z * w.z + g[i].w * w.w;
        }
    }

#pragma unroll
    for (int kk = 0; kk < 8; ++kk) {
        int k = kbase + kk;
        if (k < num_time) {
            float4 o = make_float4(acc[kk][0], acc[kk][1], acc[kk][2], acc[kk][3]);
            *(float4*)(H + (size_t)k * 1024 + pq4 * 4) = o;
        }
    }
}

// ---------------------------------------------------------------------------
// scatter block body: bin samples by k with packed records {n, i, j, k}
// ---------------------------------------------------------------------------
__device__ __forceinline__ void scatter_body(const int* __restrict__ K,
                                             const int* __restrict__ I,
                                             const int* __restrict__ J,
                                             int* __restrict__ counts,
                                             int4* __restrict__ bins,
                                             int* __restrict__ ovf_cnt,
                                             int4* __restrict__ ovf,
                                             int n, int sblk, int nsblk) {
    for (int idx = sblk * 256 + (int)threadIdx.x; idx < n; idx += nsblk * 256) {
        int k = K[idx];
        int4 rec = make_int4(idx, I[idx], J[idx], k);
        int pos = atomicAdd(&counts[k], 1);
        if (pos < BIN_CAP) {
            bins[(size_t)k * BIN_CAP + pos] = rec;
        } else {
            int o = atomicAdd(ovf_cnt, 1);
            ovf[o] = rec;
        }
    }
}

// ---------------------------------------------------------------------------
// fused_prepare: blocks [0,nbuild) run build_H, blocks [nbuild,...) scatter.
// ---------------------------------------------------------------------------
__global__ __launch_bounds__(256) void fused_prepare(
        const float* __restrict__ G, const float* __restrict__ W,
        float* __restrict__ H,
        const int* __restrict__ K, const int* __restrict__ I,
        const int* __restrict__ J, int* __restrict__ counts,
        int4* __restrict__ bins, int* __restrict__ ovf_cnt,
        int4* __restrict__ ovf, int n, int num_time,
        int nbuild, int nscatter) {
    const int b = (int)blockIdx.x;
    if (b < nbuild) {
        build_H_body(G, W, H, num_time, b);
    } else {
        scatter_body(K, I, J, counts, bins, ovf_cnt, ovf, n, b - nbuild, nscatter);
    }
}

// Standalone build_H (mid-tier fallback path)
__global__ __launch_bounds__(256) void build_H(const float* __restrict__ G,
                                               const float* __restrict__ W,
                                               float* __restrict__ H,
                                               int num_time) {
    build_H_body(G, W, H, num_time, blockIdx.x);
}

// ---------------------------------------------------------------------------
// eval helper: one sample's contraction from LDS H + registers u/v.
// ---------------------------------------------------------------------------
__device__ __forceinline__ void eval_one(const float4* __restrict__ Hs,
                                         const float4* __restrict__ u,
                                         float4 v4, int qq, int nout,
                                         float* __restrict__ out) {
    float4 acc = make_float4(0.f, 0.f, 0.f, 0.f);
#pragma unroll
    for (int p4 = 0; p4 < 8; ++p4) {
        float4 h;
        h = Hs[(p4 * 4 + 0) * 8 + qq];
        acc.x += u[p4].x * h.x; acc.y += u[p4].x * h.y;
        acc.z += u[p4].x * h.z; acc.w += u[p4].x * h.w;
        h = Hs[(p4 * 4 + 1) * 8 + qq];
        acc.x += u[p4].y * h.x; acc.y += u[p4].y * h.y;
        acc.z += u[p4].y * h.z; acc.w += u[p4].y * h.w;
        h = Hs[(p4 * 4 + 2) * 8 + qq];
        acc.x += u[p4].z * h.x; acc.y += u[p4].z * h.y;
        acc.z += u[p4].z * h.z; acc.w += u[p4].z * h.w;
        h = Hs[(p4 * 4 + 3) * 8 + qq];
        acc.x += u[p4].w * h.x; acc.y += u[p4].w * h.y;
        acc.z += u[p4].w * h.z; acc.w += u[p4].w * h.w;
    }
    float sd = acc.x * v4.x + acc.y * v4.y + acc.z * v4.z + acc.w * v4.w;
    sd += __shfl_xor(sd, 1, 64);
    sd += __shfl_xor(sd, 2, 64);
    sd += __shfl_xor(sd, 4, 64);
    if (qq == 0) out[nout] = sd;
}

// ---------------------------------------------------------------------------
// eval: block per k (grid = num_time). H[k] 4KB -> LDS (coalesced).
// Iteration 0 (covers m<=32, ~89% of blocks): record for group g loaded
// directly from bins[k*CAP+g] pre-barrier; U/V gathers issue behind it,
// overlapping H-stage + barrier. Iteration 1 record prefetched pre-barrier
// (predicated). Iterations >=1 read bins directly (group broadcast) -- no
// LDS record staging. 32 samples in flight (8-lane group per sample).
// Overflow drained grid-stride (global H).
// ---------------------------------------------------------------------------
__global__ __launch_bounds__(256) void tucker_eval_bpk(
        const float* __restrict__ U, const float* __restrict__ V,
        const float* __restrict__ H, const int* __restrict__ counts,
        const int4* __restrict__ bins, float* __restrict__ out,
        int num_time, const int* __restrict__ ovf_cnt,
        const int4* __restrict__ ovf) {
    __shared__ float4 Hs[256];               // 4 KB: H row for this k
    const int tid = threadIdx.x;
    const int k = (int)blockIdx.x;
    const int qq = tid & 7;                  // q-quad within sample group
    const int g = tid >> 3;                  // sample group 0..31
    const int4* __restrict__ bbase = bins + (size_t)k * BIN_CAP;

    // Issue all independent block-start loads:
    int m = counts[k];                       // scalar
    const float4* __restrict__ Hrow = (const float4*)(H + (size_t)k * 1024);
    float4 hreg = Hrow[tid];                 // H-stage load (4KB coalesced)
    int4 rec0 = bbase[g];                    // iter-0 record, direct (g<32)
    m = (m < BIN_CAP) ? m : BIN_CAP;

    // Iteration-1 record prefetch (predicated; ~11% of blocks have m>32).
    const bool act1 = (32 + g) < m;
    int4 rec1 = make_int4(0, 0, 0, 0);
    if (act1) rec1 = bbase[32 + g];

    // Iter-0 U/V gathers issue as soon as rec0+m land (no barrier in chain).
    // Clamp addresses against poison for inactive groups (g >= m).
    const bool act0 = (g < m);
    const int ri0 = act0 ? rec0.y : 0;
    const int rj0 = act0 ? rec0.z : 0;
    float4 u[8];
    {
        const float4* __restrict__ Ur = (const float4*)(U + (size_t)ri0 * 32);
#pragma unroll
        for (int p4 = 0; p4 < 8; ++p4) u[p4] = Ur[p4];
    }
    float4 v4 = ((const float4*)(V + (size_t)rj0 * 32))[qq];

    Hs[tid] = hreg;                          // LDS write once hreg arrives
    __syncthreads();

    // ---------------- iteration 0 (s = g) ----------------
    if (act0) eval_one(Hs, u, v4, qq, rec0.x, out);

    // ---------------- iteration 1 (s = 32+g), prefetched record ----------------
    if (act1) {
        const float4* __restrict__ Ur = (const float4*)(U + (size_t)rec1.y * 32);
        float4 u1[8];
#pragma unroll
        for (int p4 = 0; p4 < 8; ++p4) u1[p4] = Ur[p4];
        float4 v1 = ((const float4*)(V + (size_t)rec1.z * 32))[qq];
        eval_one(Hs, u1, v1, qq, rec1.x, out);
    }

    // ---------------- iterations >= 2 (m > 64, effectively never) ----------------
    for (int s0 = 64; s0 < m; s0 += 32) {
        const int s = s0 + g;
        if (s < m) {
            int4 rec = bbase[s];             // group-broadcast 16B line
            const float4* __restrict__ Ur = (const float4*)(U + (size_t)rec.y * 32);
            float4 u2[8];
#pragma unroll
            for (int p4 = 0; p4 < 8; ++p4) u2[p4] = Ur[p4];
            float4 v2 = ((const float4*)(V + (size_t)rec.z * 32))[qq];
            eval_one(Hs, u2, v2, qq, rec.x, out);
        }
    }

    // --------- overflow drain (rare/never): wave per spill record ---------
    const int cnt = *ovf_cnt;
    if (cnt > 0) {
        const int wave = tid >> 6;
        const int lane = tid & 63;
        const int gwave = k * 4 + wave;
        const int nw = (int)gridDim.x * 4;
        const int pg = lane >> 3;
        const int qq6 = lane & 7;
        for (int s = gwave; s < cnt; s += nw) {
            int4 rec = ovf[s];
            const float4* __restrict__ Hrow2 = (const float4*)(H + (size_t)rec.w * 1024);
            const float* __restrict__ Ur = U + (size_t)rec.y * 32;

            float4 acc = make_float4(0.f, 0.f, 0.f, 0.f);
#pragma unroll
            for (int it = 0; it < 4; ++it) {
                float4 h = Hrow2[lane + it * 64];
                float up = Ur[pg + it * 8];
                acc.x += up * h.x; acc.y += up * h.y;
                acc.z += up * h.z; acc.w += up * h.w;
            }
#pragma unroll
            for (int off = 8; off < 64; off <<= 1) {
                acc.x += __shfl_xor(acc.x, off, 64);
                acc.y += __shfl_xor(acc.y, off, 64);
                acc.z += __shfl_xor(acc.z, off, 64);
                acc.w += __shfl_xor(acc.w, off, 64);
            }
            float4 v4o = ((const float4*)(V + (size_t)rec.z * 32))[qq6];
            float sd = acc.x * v4o.x + acc.y * v4o.y + acc.z * v4o.z + acc.w * v4o.w;
            sd += __shfl_xor(sd, 1, 64);
            sd += __shfl_xor(sd, 2, 64);
            sd += __shfl_xor(sd, 4, 64);
            if (lane == 0) out[rec.x] = sd;
        }
    }
}

// ---------------------------------------------------------------------------
// Fallbacks for small workspace
// ---------------------------------------------------------------------------
__global__ __launch_bounds__(256) void tucker_eval(const int* __restrict__ I,
                                                   const int* __restrict__ J,
                                                   const int* __restrict__ K,
                                                   const float* __restrict__ U,
                                                   const float* __restrict__ V,
                                                   const float* __restrict__ H,
                                                   float* __restrict__ out,
                                                   int n_samples) {
    const int wave = (int)((blockIdx.x * (unsigned)blockDim.x + threadIdx.x) >> 6);
    const int lane = threadIdx.x & 63;
    if (wave >= n_samples) return;
    const int i = I[wave];
    const int j = J[wave];
    const int k = K[wave];
    const int qq = lane & 7;
    const int pg = lane >> 3;
    const float4* __restrict__ Hrow = (const float4*)(H + (size_t)k * 1024);
    const float* __restrict__ Urow = U + (size_t)i * 32;
    float4 acc = make_float4(0.f, 0.f, 0.f, 0.f);
#pragma unroll
    for (int it = 0; it < 4; ++it) {
        float4 h = Hrow[lane + it * 64];
        float up = Urow[pg + it * 8];
        acc.x += up * h.x; acc.y += up * h.y;
        acc.z += up * h.z; acc.w += up * h.w;
    }
#pragma unroll
    for (int off = 8; off < 64; off <<= 1) {
        acc.x += __shfl_xor(acc.x, off, 64);
        acc.y += __shfl_xor(acc.y, off, 64);
        acc.z += __shfl_xor(acc.z, off, 64);
        acc.w += __shfl_xor(acc.w, off, 64);
    }
    float4 v4 = ((const float4*)(V + (size_t)j * 32))[qq];
    float s = acc.x * v4.x + acc.y * v4.y + acc.z * v4.z + acc.w * v4.w;
    s += __shfl_xor(s, 1, 64);
    s += __shfl_xor(s, 2, 64);
    s += __shfl_xor(s, 4, 64);
    if (lane == 0) out[wave] = s;
}

__global__ __launch_bounds__(256) void tucker_direct(const int* __restrict__ I,
                                                     const int* __restrict__ J,
                                                     const int* __restrict__ K,
                                                     const float* __restrict__ U,
                                                     const float* __restrict__ V,
                                                     const float* __restrict__ W,
                                                     const float* __restrict__ G,
                                                     float* __restrict__ out,
                                                     int n_samples) {
    __shared__ float Gc[4 * 32 * 32];
    const int n = blockIdx.x * blockDim.x + threadIdx.x;
    const bool active = (n < n_samples);
    int i = 0, j = 0, k = 0;
    if (active) { i = I[n]; j = J[n]; k = K[n]; }
    float4 w4[8];
#pragma unroll
    for (int r4 = 0; r4 < 8; ++r4)
        w4[r4] = ((const float4*)(W + (size_t)k * 32))[r4];
    float v[32];
#pragma unroll
    for (int q4 = 0; q4 < 8; ++q4) {
        float4 t = ((const float4*)(V + (size_t)j * 32))[q4];
        v[q4 * 4 + 0] = t.x; v[q4 * 4 + 1] = t.y;
        v[q4 * 4 + 2] = t.z; v[q4 * 4 + 3] = t.w;
    }
    const float* __restrict__ Urow = U + (size_t)i * 32;
    float acc = 0.f;
    for (int c = 0; c < 8; ++c) {
        __syncthreads();
#pragma unroll
        for (int t = 0; t < 4; ++t) {
            int idx = threadIdx.x + t * 256;
            ((float4*)Gc)[idx] = ((const float4*)(G + (size_t)c * 4096))[idx];
        }
        __syncthreads();
        for (int pp = 0; pp < 4; ++pp) {
            float up = Urow[c * 4 + pp];
#pragma unroll
            for (int q = 0; q < 32; ++q) {
                float t0 = 0.f;
#pragma unroll
                for (int r4 = 0; r4 < 8; ++r4) {
                    float4 g = ((const float4*)Gc)[pp * 256 + q * 8 + r4];
                    t0 += g.x * w4[r4].x + g.y * w4[r4].y + g.z * w4[r4].z + g.w * w4[r4].w;
                }
                acc += up * v[q] * t0;
            }
        }
    }
    if (active) out[n] = acc;
}

extern "C" void kernel_launch(void* const* d_in, const int* in_sizes, int n_in,
                              void* d_out, int out_size, void* d_ws, size_t ws_size,
                              hipStream_t stream) {
    const int*   I = (const int*)d_in[0];
    const int*   J = (const int*)d_in[1];
    const int*   K = (const int*)d_in[2];
    const float* U = (const float*)d_in[3];   // [NUM_USER, 32]
    const float* V = (const float*)d_in[4];   // [NUM_ITEM, 32]
    const float* W = (const float*)d_in[5];   // [NUM_TIME, 32]
    const float* G = (const float*)d_in[6];   // [32, 32, 32]
    float* out = (float*)d_out;

    const int n_samples = in_sizes[0];
    const int num_time = in_sizes[5] / 32;

    const size_t h_bytes = (size_t)num_time * 1024 * sizeof(float);
    const size_t z_bytes = (size_t)(num_time + 1) * sizeof(int);   // counts + ovf_cnt
    const size_t z_pad = (z_bytes + 15) & ~(size_t)15;
    const size_t bins_bytes = (size_t)num_time * BIN_CAP * sizeof(int4);
    const size_t ovf_bytes = (size_t)n_samples * sizeof(int4);
    const size_t need_full = h_bytes + z_pad + bins_bytes + ovf_bytes;

    if (ws_size >= need_full) {
        float* H       = (float*)d_ws;
        int*   counts  = (int*)((char*)d_ws + h_bytes);      // num_time
        int*   ovf_cnt = counts + num_time;                  // 1 (contiguous)
        int4*  bins    = (int4*)((char*)d_ws + h_bytes + z_pad);
        int4*  ovf     = (int4*)((char*)d_ws + h_bytes + z_pad + bins_bytes);

        const int nbuild = (num_time + 7) / 8;
        const int nscatter = 512;

        hipMemsetAsync(counts, 0, z_bytes, stream);
        fused_prepare<<<nbuild + nscatter, 256, 0, stream>>>(
            G, W, H, K, I, J, counts, bins, ovf_cnt, ovf,
            n_samples, num_time, nbuild, nscatter);
        tucker_eval_bpk<<<num_time, 256, 0, stream>>>(
            U, V, H, counts, bins, out, num_time, ovf_cnt, ovf);
    } else if (ws_size >= h_bytes) {
        float* H = (float*)d_ws;
        build_H<<<(num_time + 7) / 8, 256, 0, stream>>>(G, W, H, num_time);
        const long long total_threads = (long long)n_samples * 64;
        tucker_eval<<<(int)((total_threads + 255) / 256), 256, 0, stream>>>(
            I, J, K, U, V, H, out, n_samples);
    } else {
        tucker_direct<<<(n_samples + 255) / 256, 256, 0, stream>>>(
            I, J, K, U, V, W, G, out, n_samples);
    }
}